// Round 2
// baseline (967.046 us; speedup 1.0000x reference)
//
#include <hip/hip_runtime.h>
#include <hip/hip_fp16.h>

typedef unsigned int u32;
typedef unsigned short u16;
typedef float f32x4 __attribute__((ext_vector_type(4)));
typedef short s16x8 __attribute__((ext_vector_type(8)));

static constexpr int kN = 500000;   // points
static constexpr int kC = 10000;    // clusters
static constexpr int kD = 128;      // dims

// ---------- helpers ----------
__device__ __forceinline__ u16 f2bf(float f) {  // fp32 -> bf16 RNE
  u32 b = __float_as_uint(f);
  return (u16)((b + 0x7FFFu + ((b >> 16) & 1u)) >> 16);
}
__device__ __forceinline__ float bf2f(u16 h) {
  return __uint_as_float(((u32)h) << 16);
}
// monotone float<->uint encoding so atomicMax(u32) == float max
__device__ __forceinline__ u32 fenc(float f) {
  int b = __float_as_int(f);
  return (b >= 0) ? ((u32)b | 0x80000000u) : ~((u32)b);
}
__device__ __forceinline__ float fdec(u32 u) {
  int b = (u & 0x80000000u) ? (int)(u & 0x7FFFFFFFu) : (int)(~u);
  return __int_as_float(b);
}

// ---------- W -> bf16 hi/lo split, concat [384][128] (Wv|Wk|Wq) ----------
__global__ void k_wcvt(const float* __restrict__ Wv, const float* __restrict__ Wk,
                       const float* __restrict__ Wq, u16* __restrict__ Wh,
                       u16* __restrict__ Wl) {
  int i = blockIdx.x * blockDim.x + threadIdx.x;
  if (i >= 384 * 128) return;
  int row = i >> 7, col = i & 127;
  float f = (row < 128) ? Wv[row * 128 + col]
          : (row < 256) ? Wk[(row - 128) * 128 + col]
                        : Wq[(row - 256) * 128 + col];
  u16 hb = f2bf(f);
  Wh[i] = hb;
  Wl[i] = f2bf(f - bf2f(hb));
}

// ---------- counting sort by cluster ----------
__global__ void k_hist(const int* __restrict__ cluster, int* __restrict__ hist) {
  int n = blockIdx.x * blockDim.x + threadIdx.x;
  if (n < kN) atomicAdd(hist + cluster[n], 1);
}

__global__ void k_scan(const int* __restrict__ hist, int* __restrict__ offs,
                       int* __restrict__ cur) {
  __shared__ int sh[256];
  const int t = threadIdx.x;  // 256 threads
  const int b0 = t * 40;
  const int e0 = (b0 + 40 < kC) ? b0 + 40 : kC;
  int s = 0;
  for (int i = b0; i < e0; ++i) s += hist[i];
  sh[t] = s;
  __syncthreads();
  for (int d = 1; d < 256; d <<= 1) {
    int v = (t >= d) ? sh[t - d] : 0;
    __syncthreads();
    sh[t] += v;
    __syncthreads();
  }
  int run = sh[t] - s;  // exclusive prefix
  for (int i = b0; i < e0; ++i) {
    offs[i] = run;
    cur[i] = run;
    run += hist[i];
  }
}

__global__ void k_scatter(const int* __restrict__ cluster, int* __restrict__ cur,
                          int* __restrict__ order) {
  int n = blockIdx.x * blockDim.x + threadIdx.x;
  if (n < kN) {
    int pos = atomicAdd(cur + cluster[n], 1);
    order[pos] = n;
  }
}

// ---------- projections: v,k (bf16) + qp (f16, into d_out scratch) ----------
// block = 256 thr = 4 waves; wave owns 32 points (2 m-subtiles of 16).
// split-bf16 MFMA: acc = xh*Wh + xl*Wh + xh*Wl  (fp32-equivalent)
__global__ __launch_bounds__(256, 4) void k_proj(
    const float* __restrict__ x, const u16* __restrict__ Wh,
    const u16* __restrict__ Wl, const float* __restrict__ bv,
    const float* __restrict__ bk, const float* __restrict__ bq,
    u16* __restrict__ v_bf, u16* __restrict__ k_bf, u16* __restrict__ qp_h) {
  const int lane = threadIdx.x & 63;
  const int wid = threadIdx.x >> 6;
  const int g = lane >> 4;   // 0..3
  const int r = lane & 15;   // 0..15
  const long base_pt = (long)blockIdx.x * 128 + wid * 32;

  // A fragments (x rows), hi/lo bf16.  A[row=l&15][k=8*(l>>4)+j]
  s16x8 ah[2][4], al[2][4];
#pragma unroll
  for (int ms = 0; ms < 2; ++ms) {
    long row = base_pt + ms * 16 + r;
    if (row >= kN) row = kN - 1;  // clamp (stores are predicated)
    const float* xp = x + row * 128;
#pragma unroll
    for (int kk = 0; kk < 4; ++kk) {
      const float4 f0 = *(const float4*)(xp + kk * 32 + g * 8);
      const float4 f1 = *(const float4*)(xp + kk * 32 + g * 8 + 4);
      float f[8] = {f0.x, f0.y, f0.z, f0.w, f1.x, f1.y, f1.z, f1.w};
      s16x8 h, l;
#pragma unroll
      for (int j = 0; j < 8; ++j) {
        u16 hb = f2bf(f[j]);
        h[j] = (short)hb;
        l[j] = (short)f2bf(f[j] - bf2f(hb));
      }
      ah[ms][kk] = h;
      al[ms][kk] = l;
    }
  }

  for (int nt = 0; nt < 24; ++nt) {  // 24 n-tiles of 16 dims (8 per matrix)
    const int mat = nt >> 3;               // 0=v 1=k 2=q
    const int d = (nt & 7) * 16 + r;       // dim within matrix
    const int wrow = nt * 16 + r;          // row in concat W
    s16x8 bh[4], bl[4];
#pragma unroll
    for (int kk = 0; kk < 4; ++kk) {       // B[k=8g+j][col=r] = W[wrow][k]
      bh[kk] = *(const s16x8*)(Wh + wrow * 128 + kk * 32 + g * 8);
      bl[kk] = *(const s16x8*)(Wl + wrow * 128 + kk * 32 + g * 8);
    }
    const float bias = (mat == 0) ? bv[d] : (mat == 1) ? bk[d] : bq[d];
#pragma unroll
    for (int ms = 0; ms < 2; ++ms) {
      f32x4 acc = {0.f, 0.f, 0.f, 0.f};
#pragma unroll
      for (int kk = 0; kk < 4; ++kk) {
        acc = __builtin_amdgcn_mfma_f32_16x16x32_bf16(ah[ms][kk], bh[kk], acc, 0, 0, 0);
        acc = __builtin_amdgcn_mfma_f32_16x16x32_bf16(al[ms][kk], bh[kk], acc, 0, 0, 0);
        acc = __builtin_amdgcn_mfma_f32_16x16x32_bf16(ah[ms][kk], bl[kk], acc, 0, 0, 0);
      }
      const long prow = base_pt + ms * 16 + g * 4;  // D[row=4g+j][col=r]
      if (mat == 0) {
#pragma unroll
        for (int j = 0; j < 4; ++j) {
          long pt = prow + j;
          if (pt < kN) v_bf[pt * 128 + d] = f2bf(acc[j] + bias);
        }
      } else if (mat == 1) {
#pragma unroll
        for (int j = 0; j < 4; ++j) {
          long pt = prow + j;
          if (pt < kN) k_bf[pt * 128 + d] = f2bf(acc[j] + bias);
        }
      } else {
#pragma unroll
        for (int j = 0; j < 4; ++j) {
          long pt = prow + j;
          if (pt < kN)
            qp_h[pt * 128 + d] = __half_as_ushort(__float2half_rn(acc[j] + bias));
        }
      }
    }
  }
}

// ---------- per-cluster max-pool of qp (gather via sorted order) ----------
__global__ void k_qpool(const u16* __restrict__ qp_h, const int* __restrict__ order,
                        const int* __restrict__ offs, const int* __restrict__ hist,
                        float* __restrict__ q) {
  const int c = blockIdx.x;    // one block per cluster
  const int d = threadIdx.x;   // 128 threads
  const int start = offs[c];
  const int cnt = hist[c];
  float mx = -INFINITY;
  for (int i = 0; i < cnt; ++i) {
    int n = order[start + i];
    mx = fmaxf(mx, __half2float(__ushort_as_half(qp_h[(long)n * 128 + d])));
  }
  q[(long)c * 128 + d] = mx;
}

// ---------- M[n] = dot(q[c_n], k[n]); m[c] = segment max ----------
__global__ void k_m(const u16* __restrict__ k_bf, const float* __restrict__ q,
                    const int* __restrict__ cluster, float* __restrict__ M_arr,
                    u32* __restrict__ m_enc) {
  int wid = threadIdx.x >> 6, lane = threadIdx.x & 63;
  int n = blockIdx.x * 4 + wid;  // kN % 4 == 0
  if (n >= kN) return;
  int c = cluster[n];
  u32 kb = *(const u32*)(k_bf + (long)n * 128 + lane * 2);
  float2 qv = *(const float2*)(q + (long)c * 128 + lane * 2);
  float k0 = __uint_as_float((kb & 0xFFFFu) << 16);
  float k1 = __uint_as_float(kb & 0xFFFF0000u);
  float p = k0 * qv.x + k1 * qv.y;
#pragma unroll
  for (int off = 32; off; off >>= 1) p += __shfl_xor(p, off, 64);
  if (lane == 0) {
    M_arr[n] = p;
    atomicMax(m_enc + c, fenc(p));
  }
}

// ---------- e = exp(M - m[c]); s[c] += e ----------
__global__ void k_expsum(const float* __restrict__ M_arr, const u32* __restrict__ m_enc,
                         const int* __restrict__ cluster, float* __restrict__ e_arr,
                         float* __restrict__ s_sum) {
  int n = blockIdx.x * blockDim.x + threadIdx.x;
  if (n >= kN) return;
  int c = cluster[n];
  float e = __expf(M_arr[n] - fdec(m_enc[c]));
  e_arr[n] = e;
  atomicAdd(s_sum + c, e);
}

// ---------- BN stats: sum(y), sum(y^2) per dim; also a = e/s stored ----------
__global__ void k_bnstats(const u16* __restrict__ v_bf, const float* __restrict__ e_arr,
                          const float* __restrict__ s_sum, const int* __restrict__ cluster,
                          float* __restrict__ a_arr, double* __restrict__ bn_mu,
                          double* __restrict__ bn_m2) {
  __shared__ float a_sh[512];
  const int tid = threadIdx.x;  // 128 threads
  const long p0 = (long)blockIdx.x * 512;
  for (int i = tid; i < 512; i += 128) {
    long n = p0 + i;
    float a = 0.f;
    if (n < kN) {
      a = e_arr[n] / s_sum[cluster[n]];
      a_arr[n] = a;
    }
    a_sh[i] = a;
  }
  __syncthreads();
  const int d = tid;
  long rem = kN - p0;
  int cnt = rem < 512 ? (int)rem : 512;
  float smu = 0.f, sm2 = 0.f;
#pragma unroll 4
  for (int p = 0; p < cnt; ++p) {
    float vv = bf2f(v_bf[(p0 + p) * 128 + d]);
    float y = a_sh[p] * vv;
    smu += y;
    sm2 += y * y;
  }
  atomicAdd(bn_mu + d, (double)smu);
  atomicAdd(bn_m2 + d, (double)sm2);
}

// ---------- finalize BN: scale/shift per dim ----------
__global__ void k_bnfinal(const double* __restrict__ bn_mu, const double* __restrict__ bn_m2,
                          const float* __restrict__ gamma, const float* __restrict__ beta,
                          float* __restrict__ scale, float* __restrict__ shift) {
  int d = threadIdx.x;  // 128
  double mu = bn_mu[d] / (double)kN;
  double var = bn_m2[d] / (double)kN - mu * mu;
  float inv = rsqrtf((float)var + 1e-5f);
  float sc = gamma[d] * inv;
  scale[d] = sc;
  shift[d] = beta[d] - (float)mu * sc;
}

// ---------- out = leakyrelu((a*v)*scale + shift) ----------
__global__ void k_out(const u16* __restrict__ v_bf, const float* __restrict__ a_arr,
                      const float* __restrict__ scale, const float* __restrict__ shift,
                      float* __restrict__ out) {
  long i = (long)blockIdx.x * blockDim.x + threadIdx.x;  // kN*16 slots of 8 dims
  if (i >= (long)kN * 16) return;
  long n = i >> 4;
  int d0 = (int)(i & 15) * 8;
  float a = a_arr[n];
  uint4 raw = *(const uint4*)(v_bf + n * 128 + d0);
  float4 sc0 = *(const float4*)(scale + d0);
  float4 sc1 = *(const float4*)(scale + d0 + 4);
  float4 sh0 = *(const float4*)(shift + d0);
  float4 sh1 = *(const float4*)(shift + d0 + 4);
  u32 w[4] = {raw.x, raw.y, raw.z, raw.w};
  float vv[8];
#pragma unroll
  for (int q = 0; q < 4; ++q) {
    vv[2 * q] = __uint_as_float((w[q] & 0xFFFFu) << 16);
    vv[2 * q + 1] = __uint_as_float(w[q] & 0xFFFF0000u);
  }
  float sc[8] = {sc0.x, sc0.y, sc0.z, sc0.w, sc1.x, sc1.y, sc1.z, sc1.w};
  float sh[8] = {sh0.x, sh0.y, sh0.z, sh0.w, sh1.x, sh1.y, sh1.z, sh1.w};
  float o[8];
#pragma unroll
  for (int q = 0; q < 8; ++q) {
    float y = fmaf(a * vv[q], sc[q], sh[q]);
    o[q] = (y >= 0.f) ? y : 0.2f * y;
  }
  float4 o0 = {o[0], o[1], o[2], o[3]};
  float4 o1 = {o[4], o[5], o[6], o[7]};
  *(float4*)(out + n * 128 + d0) = o0;
  *(float4*)(out + n * 128 + d0 + 4) = o1;
}

extern "C" void kernel_launch(void* const* d_in, const int* in_sizes, int n_in,
                              void* d_out, int out_size, void* d_ws, size_t ws_size,
                              hipStream_t stream) {
  const float* x = (const float*)d_in[0];
  const int* cluster = (const int*)d_in[1];
  const float* Wv = (const float*)d_in[2];
  const float* bv = (const float*)d_in[3];
  const float* Wk = (const float*)d_in[4];
  const float* bk = (const float*)d_in[5];
  const float* Wq = (const float*)d_in[6];
  const float* bq = (const float*)d_in[7];
  const float* gamma = (const float*)d_in[8];
  const float* beta = (const float*)d_in[9];
  float* out = (float*)d_out;

  char* ws = (char*)d_ws;
  // layout (bytes)
  u16* Wh = (u16*)(ws + 0);                  //    98,304
  u16* Wl = (u16*)(ws + 98304);              //    98,304 -> 196,608
  float* q = (float*)(ws + 196608);          // 5,120,000 -> 5,316,608
  u32* m_enc = (u32*)(ws + 5316608);         //    40,000 -> 5,356,608
  float* s_sum = (float*)(ws + 5356608);     //    40,000 -> 5,396,608
  double* bn_mu = (double*)(ws + 5396608);   //     1,024 -> 5,397,632
  double* bn_m2 = (double*)(ws + 5397632);   //     1,024 -> 5,398,656
  int* hist = (int*)(ws + 5398656);          //    40,000 -> 5,438,656
  // zero region: [5316608, 5438656)
  int* offs = (int*)(ws + 5438656);          //    40,000 -> 5,478,656
  int* cur = (int*)(ws + 5478656);           //    40,000 -> 5,518,656
  float* scale = (float*)(ws + 5518656);     //       512 -> 5,519,168
  float* shift = (float*)(ws + 5519168);     //       512 -> 5,519,680
  float* M_arr = (float*)(ws + 5519680);     // 2,000,000 -> 7,519,680
  float* e_arr = (float*)(ws + 7519680);     // 2,000,000 -> 9,519,680
  float* a_arr = (float*)(ws + 9519680);     // 2,000,000 -> 11,519,680
  int* order = (int*)(ws + 11519680);        // 2,000,000 -> 13,519,680
  u16* v_bf = (u16*)(ws + 13519680);         // 128,000,000 -> 141,519,680
  u16* k_bf = (u16*)(ws + 141519680);        // 128,000,000 -> 269,519,680

  // qp (f16) lives in d_out until k_out overwrites it
  u16* qp_h = (u16*)d_out;

  // zero accumulators: m_enc, s_sum, bn_mu, bn_m2, hist
  hipMemsetAsync(ws + 5316608, 0, 5438656 - 5316608, stream);

  k_wcvt<<<192, 256, 0, stream>>>(Wv, Wk, Wq, Wh, Wl);
  k_hist<<<(kN + 255) / 256, 256, 0, stream>>>(cluster, hist);
  k_scan<<<1, 256, 0, stream>>>(hist, offs, cur);
  k_scatter<<<(kN + 255) / 256, 256, 0, stream>>>(cluster, cur, order);
  k_proj<<<(kN + 127) / 128, 256, 0, stream>>>(x, Wh, Wl, bv, bk, bq,
                                               v_bf, k_bf, qp_h);
  k_qpool<<<kC, 128, 0, stream>>>(qp_h, order, offs, hist, q);
  k_m<<<kN / 4, 256, 0, stream>>>(k_bf, q, cluster, M_arr, m_enc);
  k_expsum<<<(kN + 255) / 256, 256, 0, stream>>>(M_arr, m_enc, cluster, e_arr, s_sum);
  k_bnstats<<<(kN + 511) / 512, 128, 0, stream>>>(v_bf, e_arr, s_sum, cluster, a_arr,
                                                  bn_mu, bn_m2);
  k_bnfinal<<<1, 128, 0, stream>>>(bn_mu, bn_m2, gamma, beta, scale, shift);
  k_out<<<(int)(((long)kN * 16 + 255) / 256), 256, 0, stream>>>(v_bf, a_arr, scale,
                                                                shift, out);
}

// Round 3
// 749.432 us; speedup vs baseline: 1.2904x; 1.2904x over previous
//
#include <hip/hip_runtime.h>

typedef unsigned int u32;
typedef unsigned short u16;
typedef float f32x4 __attribute__((ext_vector_type(4)));
typedef _Float16 f16x8 __attribute__((ext_vector_type(8)));
typedef _Float16 f16x4 __attribute__((ext_vector_type(4)));
typedef _Float16 f16x2 __attribute__((ext_vector_type(2)));

static constexpr int kN = 500000;   // points
static constexpr int kC = 10000;    // clusters

// ---------- W -> f16 concat [384][128] (Wv|Wk|Wq) + bias concat ----------
__global__ void k_wcvt(const float* __restrict__ Wv, const float* __restrict__ Wk,
                       const float* __restrict__ Wq, const float* __restrict__ bv,
                       const float* __restrict__ bk, const float* __restrict__ bq,
                       _Float16* __restrict__ Wc, float* __restrict__ bias_c) {
  int i = blockIdx.x * blockDim.x + threadIdx.x;
  if (i < 384) bias_c[i] = (i < 128) ? bv[i] : (i < 256) ? bk[i - 128] : bq[i - 256];
  if (i >= 384 * 128) return;
  int row = i >> 7;
  float f = (row < 128) ? Wv[i] : (row < 256) ? Wk[i - 128 * 128] : Wq[i - 256 * 128];
  Wc[i] = (_Float16)f;
}

// ---------- counting sort by cluster ----------
__global__ void k_hist(const int* __restrict__ cluster, int* __restrict__ hist) {
  int n = blockIdx.x * blockDim.x + threadIdx.x;
  if (n < kN) atomicAdd(hist + cluster[n], 1);
}

__global__ void k_scan(const int* __restrict__ hist, int* __restrict__ offs,
                       int* __restrict__ cur) {
  __shared__ int sh[256];
  const int t = threadIdx.x;  // 256 threads
  const int b0 = t * 40;
  const int e0 = (b0 + 40 < kC) ? b0 + 40 : kC;
  int s = 0;
  for (int i = b0; i < e0; ++i) s += hist[i];
  sh[t] = s;
  __syncthreads();
  for (int d = 1; d < 256; d <<= 1) {
    int v = (t >= d) ? sh[t - d] : 0;
    __syncthreads();
    sh[t] += v;
    __syncthreads();
  }
  int run = sh[t] - s;  // exclusive prefix
  for (int i = b0; i < e0; ++i) {
    offs[i] = run;
    cur[i] = run;
    run += hist[i];
  }
}

__global__ void k_scatter(const int* __restrict__ cluster, int* __restrict__ cur,
                          int* __restrict__ order) {
  int n = blockIdx.x * blockDim.x + threadIdx.x;
  if (n < kN) {
    int pos = atomicAdd(cur + cluster[n], 1);
    order[pos] = n;
  }
}

// ---------- projections into SORTED domain ----------
// D = Wc (A, [384]x[128]) x x^T (B, [128]x[points]).  Wave owns 64 sorted points.
// A frag: lane(g=l>>4, r=l&15): W[m*16+r][kk*32+8g+j]   (j=0..7)
// B frag: x[order[pbase+p*16+r]][kk*32+8g+j]
// D: lane holds D[4g+jj][r] -> dims m*16+4g+jj of sorted point pbase+p*16+r
//    -> 4 consecutive dims => packed 8B store.
__global__ __launch_bounds__(256) void k_proj(
    const float* __restrict__ x, const int* __restrict__ order,
    const _Float16* __restrict__ Wc, const float* __restrict__ bias_c,
    _Float16* __restrict__ v_s, _Float16* __restrict__ k_s,
    _Float16* __restrict__ qp_s) {
  const int lane = threadIdx.x & 63, wid = threadIdx.x >> 6;
  const int g = lane >> 4, r = lane & 15;
  const long pbase = (long)blockIdx.x * 256 + wid * 64;

  int rows[4];
#pragma unroll
  for (int p = 0; p < 4; ++p) {
    long i = pbase + p * 16 + r;
    rows[p] = order[i < kN ? i : (kN - 1)];
  }
  f16x8 xf[4][4];
#pragma unroll
  for (int p = 0; p < 4; ++p) {
    const float* xp = x + (long)rows[p] * 128;
#pragma unroll
    for (int kk = 0; kk < 4; ++kk) {
      float4 f0 = *(const float4*)(xp + kk * 32 + g * 8);
      float4 f1 = *(const float4*)(xp + kk * 32 + g * 8 + 4);
      f16x8 h;
      h[0] = (_Float16)f0.x; h[1] = (_Float16)f0.y;
      h[2] = (_Float16)f0.z; h[3] = (_Float16)f0.w;
      h[4] = (_Float16)f1.x; h[5] = (_Float16)f1.y;
      h[6] = (_Float16)f1.z; h[7] = (_Float16)f1.w;
      xf[p][kk] = h;
    }
  }
#pragma unroll
  for (int m = 0; m < 24; ++m) {
    const _Float16* wrow = Wc + (m * 16 + r) * 128;
    f16x8 wf[4];
#pragma unroll
    for (int kk = 0; kk < 4; ++kk)
      wf[kk] = *(const f16x8*)(wrow + kk * 32 + g * 8);
    float4 b4 = *(const float4*)(bias_c + m * 16 + g * 4);
    _Float16* outp = (m < 8) ? v_s : (m < 16) ? k_s : qp_s;
    const int del = (m & 7) * 16 + g * 4;  // element offset within 128-dim row
#pragma unroll
    for (int p = 0; p < 4; ++p) {
      f32x4 acc = {0.f, 0.f, 0.f, 0.f};
#pragma unroll
      for (int kk = 0; kk < 4; ++kk)
        acc = __builtin_amdgcn_mfma_f32_16x16x32_f16(wf[kk], xf[p][kk], acc, 0, 0, 0);
      long i = pbase + p * 16 + r;
      if (i < kN) {
        f16x4 h;
        h[0] = (_Float16)(acc[0] + b4.x);
        h[1] = (_Float16)(acc[1] + b4.y);
        h[2] = (_Float16)(acc[2] + b4.z);
        h[3] = (_Float16)(acc[3] + b4.w);
        *(f16x4*)(outp + i * 128 + del) = h;
      }
    }
  }
}

// ---------- fused per-cluster: q = max-pool(qp), M = q.k, softmax -> a ----------
__global__ __launch_bounds__(256) void k_attn(
    const _Float16* __restrict__ qp_s, const _Float16* __restrict__ k_s,
    const int* __restrict__ offs, const int* __restrict__ hist,
    float* __restrict__ M_s, float* __restrict__ a_s) {
  __shared__ float q_sh[128];
  __shared__ float red[512];
  const int c = blockIdx.x;
  const int start = offs[c], cnt = hist[c];
  if (cnt == 0) return;
  const int t = threadIdx.x, lane = t & 63, wid = t >> 6;
  // phase 1: per-dim max over the cluster's qp rows
  {
    const int d2 = (t & 63) * 2, rg = t >> 6;
    float m0 = -INFINITY, m1 = -INFINITY;
    for (int i = rg; i < cnt; i += 4) {
      f16x2 h = *(const f16x2*)(qp_s + (long)(start + i) * 128 + d2);
      m0 = fmaxf(m0, (float)h[0]);
      m1 = fmaxf(m1, (float)h[1]);
    }
    red[t] = m0;
    red[t + 256] = m1;
  }
  __syncthreads();
  if (t < 64) {
    float q0 = fmaxf(fmaxf(red[t], red[t + 64]), fmaxf(red[t + 128], red[t + 192]));
    float q1 = fmaxf(fmaxf(red[t + 256], red[t + 320]), fmaxf(red[t + 384], red[t + 448]));
    q_sh[2 * t] = q0;
    q_sh[2 * t + 1] = q1;
  }
  __syncthreads();
  // phase 2: M_i = dot(q, k_i); track max
  float wmax = -INFINITY;
  {
    const float q0 = q_sh[lane * 2], q1 = q_sh[lane * 2 + 1];
    for (int i = wid; i < cnt; i += 4) {
      f16x2 h = *(const f16x2*)(k_s + (long)(start + i) * 128 + lane * 2);
      float p = fmaf(q0, (float)h[0], q1 * (float)h[1]);
#pragma unroll
      for (int off = 32; off; off >>= 1) p += __shfl_xor(p, off, 64);
      if (lane == 0) M_s[start + i] = p;
      wmax = fmaxf(wmax, p);
    }
  }
  if (lane == 0) red[wid] = wmax;
  __syncthreads();
  const float m = fmaxf(fmaxf(red[0], red[1]), fmaxf(red[2], red[3]));
  // phase 3: e = exp(M-m), s = sum, a = e/s
  float lsum = 0.f;
  for (int i = t; i < cnt; i += 256) {
    float e = __expf(M_s[start + i] - m);
    a_s[start + i] = e;
    lsum += e;
  }
#pragma unroll
  for (int off = 32; off; off >>= 1) lsum += __shfl_xor(lsum, off, 64);
  if (lane == 0) red[4 + wid] = lsum;
  __syncthreads();
  const float inv = 1.f / (red[4] + red[5] + red[6] + red[7]);
  for (int i = t; i < cnt; i += 256) a_s[start + i] *= inv;
}

// ---------- BN stats: per-block partial sums of y, y^2 per dim ----------
__global__ __launch_bounds__(256) void k_bnstats(
    const _Float16* __restrict__ v_s, const float* __restrict__ a_s,
    float* __restrict__ part_mu, float* __restrict__ part_m2) {
  const int t = threadIdx.x;
  const int d2 = (t & 63) * 2, rg = t >> 6;
  float s0 = 0.f, s1 = 0.f, p0 = 0.f, p1 = 0.f;
  for (long base = (long)blockIdx.x * 4; base < kN; base += (long)gridDim.x * 4) {
    long row = base + rg;
    if (row < kN) {
      float a = a_s[row];
      f16x2 h = *(const f16x2*)(v_s + row * 128 + d2);
      float y0 = a * (float)h[0], y1 = a * (float)h[1];
      s0 += y0; s1 += y1; p0 += y0 * y0; p1 += y1 * y1;
    }
  }
  __shared__ float red[1024];
  red[t] = s0; red[t + 256] = s1; red[t + 512] = p0; red[t + 768] = p1;
  __syncthreads();
  if (t < 64) {
    float a0 = red[t] + red[t + 64] + red[t + 128] + red[t + 192];
    float a1 = red[t + 256] + red[t + 320] + red[t + 384] + red[t + 448];
    float b0 = red[t + 512] + red[t + 576] + red[t + 640] + red[t + 704];
    float b1 = red[t + 768] + red[t + 832] + red[t + 896] + red[t + 960];
    part_mu[blockIdx.x * 128 + 2 * t] = a0;
    part_mu[blockIdx.x * 128 + 2 * t + 1] = a1;
    part_m2[blockIdx.x * 128 + 2 * t] = b0;
    part_m2[blockIdx.x * 128 + 2 * t + 1] = b1;
  }
}

// ---------- reduce partials (f64), produce scale/shift ----------
__global__ void k_bnred(const float* __restrict__ part_mu, const float* __restrict__ part_m2,
                        const float* __restrict__ gamma, const float* __restrict__ beta,
                        float* __restrict__ scale, float* __restrict__ shift) {
  const int d = threadIdx.x;  // 128
  double mu = 0.0, m2 = 0.0;
  for (int b = 0; b < 1024; ++b) {
    mu += (double)part_mu[b * 128 + d];
    m2 += (double)part_m2[b * 128 + d];
  }
  mu /= (double)kN;
  double var = m2 / (double)kN - mu * mu;
  double inv = 1.0 / sqrt(var + 1e-5);
  float sc = gamma[d] * (float)inv;
  scale[d] = sc;
  shift[d] = beta[d] - (float)mu * sc;
}

// ---------- out[order[i]] = leakyrelu((a*v)*scale + shift) ----------
__global__ __launch_bounds__(256) void k_out(
    const _Float16* __restrict__ v_s, const float* __restrict__ a_s,
    const int* __restrict__ order, const float* __restrict__ scale,
    const float* __restrict__ shift, float* __restrict__ out) {
  const int t = threadIdx.x;
  const int d2 = (t & 63) * 2, rg = t >> 6;
  long i = (long)blockIdx.x * 4 + rg;
  if (i >= kN) return;
  int n = order[i];
  float a = a_s[i];
  f16x2 h = *(const f16x2*)(v_s + i * 128 + d2);
  float2 sc = *(const float2*)(scale + d2);
  float2 sh = *(const float2*)(shift + d2);
  float y0 = fmaf(a * (float)h[0], sc.x, sh.x);
  float y1 = fmaf(a * (float)h[1], sc.y, sh.y);
  y0 = y0 >= 0.f ? y0 : 0.2f * y0;
  y1 = y1 >= 0.f ? y1 : 0.2f * y1;
  *(float2*)(out + (long)n * 128 + d2) = make_float2(y0, y1);
}

extern "C" void kernel_launch(void* const* d_in, const int* in_sizes, int n_in,
                              void* d_out, int out_size, void* d_ws, size_t ws_size,
                              hipStream_t stream) {
  const float* x = (const float*)d_in[0];
  const int* cluster = (const int*)d_in[1];
  const float* Wv = (const float*)d_in[2];
  const float* bv = (const float*)d_in[3];
  const float* Wk = (const float*)d_in[4];
  const float* bk = (const float*)d_in[5];
  const float* Wq = (const float*)d_in[6];
  const float* bq = (const float*)d_in[7];
  const float* gamma = (const float*)d_in[8];
  const float* beta = (const float*)d_in[9];
  float* out = (float*)d_out;

  char* ws = (char*)d_ws;
  // layout (bytes)
  _Float16* Wc = (_Float16*)(ws + 0);        //    98,304
  float* bias_c = (float*)(ws + 98304);      //     1,536 -> 99,840
  int* hist = (int*)(ws + 99840);            //    40,000 -> 139,840
  int* offs = (int*)(ws + 139840);           //    40,000 -> 179,840
  int* cur = (int*)(ws + 179840);            //    40,000 -> 219,840
  float* scale = (float*)(ws + 219840);      //       512 -> 220,352
  float* shift = (float*)(ws + 220352);      //       512 -> 220,864
  float* M_s = (float*)(ws + 220864);        // 2,000,000 -> 2,220,864
  float* a_s = (float*)(ws + 2220864);       // 2,000,000 -> 4,220,864
  int* order = (int*)(ws + 4220864);         // 2,000,000 -> 6,220,864
  float* part_mu = (float*)(ws + 6220864);   //   524,288 -> 6,745,152
  float* part_m2 = (float*)(ws + 6745152);   //   524,288 -> 7,269,440
  _Float16* v_s = (_Float16*)(ws + 7269440);     // 128,000,000 -> 135,269,440
  _Float16* k_s = (_Float16*)(ws + 135269440);   // 128,000,000 -> 263,269,440
  // qp (f16, sorted) lives in d_out until k_out overwrites it
  _Float16* qp_s = (_Float16*)d_out;

  hipMemsetAsync(hist, 0, 40000, stream);  // only hist needs zeroing

  k_wcvt<<<192, 256, 0, stream>>>(Wv, Wk, Wq, bv, bk, bq, Wc, bias_c);
  k_hist<<<(kN + 255) / 256, 256, 0, stream>>>(cluster, hist);
  k_scan<<<1, 256, 0, stream>>>(hist, offs, cur);
  k_scatter<<<(kN + 255) / 256, 256, 0, stream>>>(cluster, cur, order);
  k_proj<<<(kN + 255) / 256, 256, 0, stream>>>(x, order, Wc, bias_c, v_s, k_s, qp_s);
  k_attn<<<kC, 256, 0, stream>>>(qp_s, k_s, offs, hist, M_s, a_s);
  k_bnstats<<<1024, 256, 0, stream>>>(v_s, a_s, part_mu, part_m2);
  k_bnred<<<1, 128, 0, stream>>>(part_mu, part_m2, gamma, beta, scale, shift);
  k_out<<<(kN + 3) / 4, 256, 0, stream>>>(v_s, a_s, order, scale, shift, out);
}